// Round 1
// baseline (1414.388 us; speedup 1.0000x reference)
//
#include <hip/hip_runtime.h>
#include <hip/hip_bf16.h>

// Problem constants (from reference): B=64, NCLS=200 -> BN rows = 12800
#define BROWS  12800
#define TSTEPS 8
#define EMB    300
#define EMBP   320          // EMB padded to /64, x-slot width (5 K-tiles)
#define RNN    512
#define NG     2048         // 4*RNN gate width
#define K1     832          // EMBP + RNN  (layer-1 concat GEMM K), 13 K-tiles
#define K2     1024         // RNN + RNN   (layer-2 concat GEMM K), 16 K-tiles

typedef short bf16x8 __attribute__((ext_vector_type(8)));   // 8 bf16 in 4 VGPRs
typedef float f32x4  __attribute__((ext_vector_type(4)));
typedef __hip_bfloat16 bf16;

__device__ __forceinline__ float sigmoidf_(float x) { return 1.f / (1.f + __expf(-x)); }
__device__ __forceinline__ float tanhf_(float x)    { return 1.f - 2.f / (__expf(2.f * x) + 1.f); }

// async global->LDS, 16B per lane. LDS dest = wave-uniform base + lane*16.
__device__ __forceinline__ void gl_lds16(const bf16* g, bf16* l) {
    __builtin_amdgcn_global_load_lds(
        (const __attribute__((address_space(1))) void*)g,
        (__attribute__((address_space(3))) void*)l,
        16, 0, 0);
}

// ---------------------------------------------------------------------------
// Weight repack (unchanged, round-3 proven): fp32 -> bf16, K-concat LINEAR
// row-major [N=2048][K], GATE-INTERLEAVED row permutation: output row n:
//   w = n&15 (unit), g = (n>>4)&3 (gate i,f,g,o), b = n>>6 (unit group)
//   original row = g*512 + b*16 + w
// => each wave's 64-col span = [i|f|g|o] of the same 16 units.
// ---------------------------------------------------------------------------
__global__ void convert_weights(const float* __restrict__ Wih1, const float* __restrict__ Whh1,
                                const float* __restrict__ Wih2, const float* __restrict__ Whh2,
                                const float* __restrict__ bih1, const float* __restrict__ bhh1,
                                const float* __restrict__ bih2, const float* __restrict__ bhh2,
                                bf16* __restrict__ Wc1, bf16* __restrict__ Wc2,
                                float* __restrict__ Bp1, float* __restrict__ Bp2) {
    int idx = blockIdx.x * 256 + threadIdx.x;
    const int n1 = NG * K1;
    const int n2 = NG * K2;
    if (idx < n1) {
        int n = idx / K1, k = idx - n * K1;
        int on = ((n >> 4) & 3) * RNN + (n >> 6) * 16 + (n & 15);
        float v = 0.f;
        if (k < EMB)        v = Wih1[on * EMB + k];
        else if (k >= EMBP) v = Whh1[on * RNN + (k - EMBP)];
        Wc1[idx] = __float2bfloat16(v);
    }
    if (idx < n2) {
        int n = idx >> 10, k = idx & (K2 - 1);
        int on = ((n >> 4) & 3) * RNN + (n >> 6) * 16 + (n & 15);
        float v = (k < RNN) ? Wih2[on * RNN + k] : Whh2[on * RNN + (k - RNN)];
        Wc2[idx] = __float2bfloat16(v);
    }
    if (idx < NG) {
        int on = ((idx >> 4) & 3) * RNN + (idx >> 6) * 16 + (idx & 15);
        Bp1[idx] = bih1[on] + bhh1[on];
        Bp2[idx] = bih2[on] + bhh2[on];
    }
}

// ---------------------------------------------------------------------------
// Embedding gather + tanh -> Xbuf [BROWS][320] (cols 300..319 zero pad).
// ---------------------------------------------------------------------------
__global__ void embed_step(const int* __restrict__ sent, const float* __restrict__ w2v,
                           bf16* __restrict__ Xbuf, int t) {
    int row = blockIdx.x;
    int col = threadIdx.x;                 // 0..319
    int id  = sent[row * TSTEPS + t];
    float v = (col < EMB) ? tanhf_(w2v[id * EMB + col]) : 0.f;
    Xbuf[(size_t)row * EMBP + col] = __float2bfloat16(v);
}

// ---------------------------------------------------------------------------
// ROUND-8: 256x256-tile, 8-wave, counted-vmcnt pipelined GEMM+LSTM
// (port of the verified 256^2 phase-split schedule: T2 swizzle + T3/T4
//  counted vmcnt + T5 setprio + T1 XCD swizzle).
//
// Geometry: 512 thr = 8 waves (2M x 4N); wave tile 128x64 = 8x4 MFMA frags;
// BK=64; LDS = 2 parity x (A 2x[128][64] + B 2x[128][64]) bf16 = 128 KiB
// (extern dynamic). 1 block/CU. acc[8][4] f32x4 = 128 regs;
// __launch_bounds__(512,2) -> 256-reg unified budget.
//
// Per K-tile t (buffer p = t&1), 4 phases, RAW s_barrier (no vmcnt drain):
//  g1: ds_read A0-3,B0-1 (12 x b128) ; MFMA(m-lo,n-lo) ; bar
//  g2: ds_read A4-7 (8)              ; MFMA(m-hi,n-lo) ; lgkm(0) ; bar
//      -> ALL A-region + B0-1 reads complete block-wide after this bar
//  g3: stage A-halves of tile t+2 into p (regions consumed by g2) ;
//      ds_read B2-3 (4) ; MFMA(m-lo,n-hi) ; lgkm(0) ; bar
//  g4: stage B-halves of tile t+2 (B regions consumed by g3) ;
//      MFMA(m-hi,n-hi) ; s_waitcnt vmcnt(8) ; bar
// vmcnt(8) = this group's own 8 stage-loads stay in flight; everything
// older (tile t+1's 8 loads, staged last group) is confirmed -> tile t+1
// is ready for the next group's g1 reads. Never drains to 0 mid-loop.
// Prologue: stage tiles 0,1 (16 loads) ; vmcnt(8) ; bar.
// Tail: groups with no stage use vmcnt(0) to drain the last tile.
//
// LDS swizzle (proven, zero-conflict): linear dest chunk ch holds global
// k-chunk (ch&7)^(row&7); reads use ((q+4*kk)^(r&7))*8. Keeps the
// global_load_lds dest linear (both-sides-or-neither rule).
//
// Epilogue identical to round-3 core: gates i,f,g,o of one (row,unit) land
// in one thread (j = gate); c' = sig(f)*c + sig(i)*tanh(g); h = sig(o)*
// tanh(c'); h routed through LDS transpose (stride 72) for coalesced 16B
// global stores.
//
// T1: bijective XCD swizzle over 400 blocks (400%8==0): each XCD gets a
// contiguous bm range -> A panels L2-resident.
// ---------------------------------------------------------------------------
#define BM 256
#define BN 256

#define BAR()   __builtin_amdgcn_s_barrier()
#define LGKM0() do { asm volatile("s_waitcnt lgkmcnt(0)" ::: "memory"); \
                     __builtin_amdgcn_sched_barrier(0); } while (0)
#define VMC(n)  do { asm volatile("s_waitcnt vmcnt(" #n ")" ::: "memory"); \
                     __builtin_amdgcn_sched_barrier(0); } while (0)

__global__ __launch_bounds__(512, 2) void gemm_lstm(
        const bf16* __restrict__ Ax, int ldx, int ksplit,
        const bf16* __restrict__ Ah, int ldh_in,
        const bf16* __restrict__ W,
        const float* __restrict__ Bp,
        float* __restrict__ cst,
        bf16* __restrict__ hdst, int ldh_out, int offh,
        float* __restrict__ outf, int en_out,
        int K) {
    extern __shared__ __attribute__((aligned(16))) bf16 sh[];   // 131072 B

    const int tid  = threadIdx.x;
    const int lane = tid & 63;
    const int wave = tid >> 6;              // 0..7
    const int wm   = wave >> 2, wn = wave & 3;

    // T1: XCD-aware bijective swizzle (grid 8x50 = 400 blocks, x fastest)
    const int p0 = blockIdx.y * 8 + blockIdx.x;
    const int lb = (p0 & 7) * 50 + (p0 >> 3);
    const int bn = lb & 7;                  // gate-col block, fastest logical
    const int bm = lb >> 3;                 // row block

    const int r = lane & 15, q = lane >> 4;
    const int NT = K >> 6;

    f32x4 acc[8][4];
#pragma unroll
    for (int i = 0; i < 8; ++i)
#pragma unroll
        for (int j = 0; j < 4; ++j)
#pragma unroll
            for (int rr = 0; rr < 4; ++rr) acc[i][j][rr] = 0.f;

    // staging geometry: chunk ch = c*512+tid; row = ch>>3 in [0,128);
    // global k-chunk = (ch&7)^(row&7); LDS dest linear (ch*8 elements)
    int srow[2], scol[2];
#pragma unroll
    for (int c = 0; c < 2; ++c) {
        int ch = c * 512 + tid;
        srow[c] = ch >> 3;
        scol[c] = ((ch & 7) ^ (srow[c] & 7)) * 8;
    }

    auto stageA = [&](int tile) {
        int kb = tile << 6;
        const bf16* src; int ld, ko;
        if (kb < ksplit) { src = Ax; ld = ldx;    ko = kb; }
        else             { src = Ah; ld = ldh_in; ko = kb - ksplit; }
        src += (size_t)(bm * BM) * ld;
        bf16* dst = sh + (tile & 1) * 32768;
#pragma unroll
        for (int h = 0; h < 2; ++h)
#pragma unroll
            for (int c = 0; c < 2; ++c) {
                int ch = c * 512 + tid;
                gl_lds16(src + (size_t)(h * 128 + srow[c]) * ld + ko + scol[c],
                         dst + h * 8192 + ch * 8);
            }
    };
    auto stageB = [&](int tile) {
        int kb = tile << 6;
        const bf16* src = W + (size_t)(bn * BN) * K;
        bf16* dst = sh + (tile & 1) * 32768 + 16384;
#pragma unroll
        for (int h = 0; h < 2; ++h)
#pragma unroll
            for (int c = 0; c < 2; ++c) {
                int ch = c * 512 + tid;
                gl_lds16(src + (size_t)(h * 128 + srow[c]) * K + kb + scol[c],
                         dst + h * 8192 + ch * 8);
            }
    };

    // prologue: tiles 0 and 1 in flight; confirm tile 0 (8 newest may fly)
    stageA(0); stageB(0);
    stageA(1); stageB(1);
    VMC(8);
    BAR();

    bf16x8 af[8][2], bfr[4][2];
    for (int t = 0; t < NT; ++t) {
        const bf16* base = sh + (t & 1) * 32768;
        const bf16* bA = base + wm * 8192;
        const bf16* bB = base + 16384 + (wn >> 1) * 8192 + (wn & 1) * 4096;

        // ---- g1: A0-3 + B0-1 reads; MFMA (m-lo, n-lo)
#pragma unroll
        for (int i = 0; i < 4; ++i)
#pragma unroll
            for (int kk = 0; kk < 2; ++kk)
                af[i][kk] = *(const bf16x8*)(bA + (i * 16 + r) * 64 + (((q + 4 * kk) ^ (r & 7)) * 8));
#pragma unroll
        for (int j = 0; j < 2; ++j)
#pragma unroll
            for (int kk = 0; kk < 2; ++kk)
                bfr[j][kk] = *(const bf16x8*)(bB + (j * 16 + r) * 64 + (((q + 4 * kk) ^ (r & 7)) * 8));
        __builtin_amdgcn_s_setprio(1);
#pragma unroll
        for (int kk = 0; kk < 2; ++kk)
#pragma unroll
            for (int i = 0; i < 4; ++i)
#pragma unroll
                for (int j = 0; j < 2; ++j)
                    acc[i][j] = __builtin_amdgcn_mfma_f32_16x16x32_bf16(
                        af[i][kk], bfr[j][kk], acc[i][j], 0, 0, 0);
        __builtin_amdgcn_s_setprio(0);
        BAR();

        // ---- g2: A4-7 reads; MFMA (m-hi, n-lo); all A/B0-1 reads complete
#pragma unroll
        for (int i = 4; i < 8; ++i)
#pragma unroll
            for (int kk = 0; kk < 2; ++kk)
                af[i][kk] = *(const bf16x8*)(bA + (i * 16 + r) * 64 + (((q + 4 * kk) ^ (r & 7)) * 8));
        __builtin_amdgcn_s_setprio(1);
#pragma unroll
        for (int kk = 0; kk < 2; ++kk)
#pragma unroll
            for (int i = 4; i < 8; ++i)
#pragma unroll
                for (int j = 0; j < 2; ++j)
                    acc[i][j] = __builtin_amdgcn_mfma_f32_16x16x32_bf16(
                        af[i][kk], bfr[j][kk], acc[i][j], 0, 0, 0);
        __builtin_amdgcn_s_setprio(0);
        LGKM0();
        BAR();

        // ---- g3: stage A(t+2) over consumed A regions; B2-3 reads; MFMA (m-lo, n-hi)
        if (t + 2 < NT) stageA(t + 2);
#pragma unroll
        for (int j = 2; j < 4; ++j)
#pragma unroll
            for (int kk = 0; kk < 2; ++kk)
                bfr[j][kk] = *(const bf16x8*)(bB + (j * 16 + r) * 64 + (((q + 4 * kk) ^ (r & 7)) * 8));
        __builtin_amdgcn_s_setprio(1);
#pragma unroll
        for (int kk = 0; kk < 2; ++kk)
#pragma unroll
            for (int i = 0; i < 4; ++i)
#pragma unroll
                for (int j = 2; j < 4; ++j)
                    acc[i][j] = __builtin_amdgcn_mfma_f32_16x16x32_bf16(
                        af[i][kk], bfr[j][kk], acc[i][j], 0, 0, 0);
        __builtin_amdgcn_s_setprio(0);
        LGKM0();
        BAR();

        // ---- g4: stage B(t+2); MFMA (m-hi, n-hi); counted vmcnt
        if (t + 2 < NT) stageB(t + 2);
        __builtin_amdgcn_s_setprio(1);
#pragma unroll
        for (int kk = 0; kk < 2; ++kk)
#pragma unroll
            for (int i = 4; i < 8; ++i)
#pragma unroll
                for (int j = 2; j < 4; ++j)
                    acc[i][j] = __builtin_amdgcn_mfma_f32_16x16x32_bf16(
                        af[i][kk], bfr[j][kk], acc[i][j], 0, 0, 0);
        __builtin_amdgcn_s_setprio(0);
        if (t + 2 < NT) { VMC(8); } else { VMC(0); }
        BAR();
    }
    __syncthreads();   // full drain; LDS is now reusable as h-xpose buffer

    // ---- fused LSTM epilogue ----
    // C/D mapping (m89/m91-verified): col = lane&15, row = (lane>>4)*4 + reg
    const int colb = bn * BN + wn * 64;
    const int u    = (bn * 4 + wn) * 16 + r;       // global unit index 0..511
    const float bi = Bp[colb + r];
    const float bff = Bp[colb + 16 + r];
    const float bg = Bp[colb + 32 + r];
    const float bo = Bp[colb + 48 + r];

    float cc[8][4];
#pragma unroll
    for (int i = 0; i < 8; ++i)
#pragma unroll
        for (int rr = 0; rr < 4; ++rr) {
            int row = bm * BM + wm * 128 + i * 16 + q * 4 + rr;
            cc[i][rr] = cst[(size_t)row * RNN + u];
        }

#define HLD 72   // h-xpose row stride: 144B rows (16B-aligned)
#pragma unroll
    for (int i = 0; i < 8; ++i) {
#pragma unroll
        for (int rr = 0; rr < 4; ++rr) {
            int rowl = wm * 128 + i * 16 + q * 4 + rr;       // row in block
            int row  = bm * BM + rowl;
            size_t cidx = (size_t)row * RNN + u;
            float gi = acc[i][0][rr] + bi;
            float gf = acc[i][1][rr] + bff;
            float gg = acc[i][2][rr] + bg;
            float go = acc[i][3][rr] + bo;
            float cn = sigmoidf_(gf) * cc[i][rr] + sigmoidf_(gi) * tanhf_(gg);
            float h  = sigmoidf_(go) * tanhf_(cn);
            cst[cidx] = cn;
            if (en_out) outf[cidx] = h;
            sh[rowl * HLD + wn * 16 + r] = __float2bfloat16(h);
        }
    }
    __syncthreads();

    // coalesced h stores: 256 rows x 64 units bf16; 16B x 2048 chunks
#pragma unroll
    for (int hh = 0; hh < 4; ++hh) {
        int t2   = hh * 512 + tid;         // 0..2047
        int rowl = t2 >> 3;                // 0..255
        int c8   = (t2 & 7) * 8;           // 0..56
        uint4 v  = *(const uint4*)&sh[rowl * HLD + c8];
        int row  = bm * BM + rowl;
        int gcol = bn * 64 + c8;           // unit col within [0,512)
        *(uint4*)&hdst[(size_t)row * ldh_out + offh + gcol] = v;
    }
#undef HLD
}

// ---------------------------------------------------------------------------
// Workspace layout (unchanged; total 120,668,160 B):
//   c1   fp32 [12800][512]   off 0
//   c2   fp32 [12800][512]   off  26,214,400
//   A2a  bf16 [12800][1024]  off  52,428,800
//   A2b  bf16 [12800][1024]  off  78,643,200
//   Xbuf bf16 [12800][320]   off 104,857,600
//   Wc1  bf16 [2048][832]    off 113,049,600
//   Wc2  bf16 [2048][1024]   off 116,457,472
//   Bp1  fp32 [2048]         off 120,651,776
//   Bp2  fp32 [2048]         off 120,659,968
// Ping-pong unchanged: L1(t) reads A2[prv][0,512), writes A2[cur][0,512);
// L2(t) reads A2[cur], writes A2[prv][512,1024). No dispatch reads and
// writes the same buffer.
// ---------------------------------------------------------------------------
extern "C" void kernel_launch(void* const* d_in, const int* in_sizes, int n_in,
                              void* d_out, int out_size, void* d_ws, size_t ws_size,
                              hipStream_t stream) {
    (void)in_sizes; (void)n_in; (void)out_size; (void)ws_size;
    const int*   sent = (const int*)d_in[0];
    const float* w2v  = (const float*)d_in[1];
    const float* Wih1 = (const float*)d_in[2];
    const float* Whh1 = (const float*)d_in[3];
    const float* bih1 = (const float*)d_in[4];
    const float* bhh1 = (const float*)d_in[5];
    const float* Wih2 = (const float*)d_in[6];
    const float* Whh2 = (const float*)d_in[7];
    const float* bih2 = (const float*)d_in[8];
    const float* bhh2 = (const float*)d_in[9];
    float* out = (float*)d_out;

    char* ws = (char*)d_ws;
    float* c1   = (float*)(ws);
    float* c2   = (float*)(ws + 26214400);
    bf16*  A2[2];
    A2[0] = (bf16*)(ws + 52428800);
    A2[1] = (bf16*)(ws + 78643200);
    bf16*  Xbuf = (bf16*) (ws + 104857600);
    bf16*  Wc1  = (bf16*) (ws + 113049600);
    bf16*  Wc2  = (bf16*) (ws + 116457472);
    float* Bp1  = (float*)(ws + 120651776);
    float* Bp2  = (float*)(ws + 120659968);

    // one-time: allow 128 KiB dynamic LDS for the GEMM kernel
    static int shmem_set = 0;
    if (!shmem_set) {
        (void)hipFuncSetAttribute((const void*)gemm_lstm,
                                  hipFuncAttributeMaxDynamicSharedMemorySize, 131072);
        shmem_set = 1;
    }

    // zero c1,c2,A2a,A2b (ws is re-poisoned 0xAA before every call)
    hipMemsetAsync(ws, 0, 104857600, stream);

    convert_weights<<<dim3((NG * K2 + 255) / 256), dim3(256), 0, stream>>>(
        Wih1, Whh1, Wih2, Whh2, bih1, bhh1, bih2, bhh2, Wc1, Wc2, Bp1, Bp2);

    for (int t = 0; t < TSTEPS; ++t) {
        const int cur = t & 1, prv = cur ^ 1;

        // x_t -> Xbuf (cols 300..319 zeroed)
        embed_step<<<dim3(BROWS), dim3(EMBP), 0, stream>>>(sent, w2v, Xbuf, t);

        // layer 1: gates = [x_t | h1(t-1)] @ Wc1^T, fused update
        gemm_lstm<<<dim3(NG / BN, BROWS / BM), dim3(512), 131072, stream>>>(
            Xbuf, EMBP, EMBP,
            A2[prv], K2,
            Wc1, Bp1, c1,
            A2[cur], K2, 0,
            (float*)nullptr, 0, K1);

        // layer 2: gates = [h1(t) | h2(t-1)] @ Wc2^T, fused update
        gemm_lstm<<<dim3(NG / BN, BROWS / BM), dim3(512), 131072, stream>>>(
            (const bf16*)nullptr, 0, 0,
            A2[cur], K2,
            Wc2, Bp2, c2,
            A2[prv], K2, RNN,
            out, (t == TSTEPS - 1) ? 1 : 0, K2);
    }
}